// Round 14
// baseline (238.563 us; speedup 1.0000x reference)
//
#include <hip/hip_runtime.h>
#include <hip/hip_bf16.h>
#include <stdint.h>

#define NW   1024
#define D    768
#define NS   8192
#define MAXW 30
#define FFNN 1000
#define FEAT 20

typedef __attribute__((ext_vector_type(8))) short bf16x8;
typedef __attribute__((ext_vector_type(4))) float f32x4;
#define MFMA16 __builtin_amdgcn_mfma_f32_16x16x32_bf16

// ws layout (float-slot offsets)
#define O_P    0                          // 3*1024*1000 fp32 P1,P2,P3 (later W2T 1024-stride)
#define O_P4   3072000                    // 30*1000
#define O_HS   3102000                    // 1024
#define O_ATT  3103024                    // SEL/SELKEY/CNT/PRANK/RANK/PERM region
#define O_PS   3365168                    // 8192*16 (PS; later MC/ME/MG masks)
#define O_H1R  3504432                    // H1 hi/lo bf16 (stride 1000); earlier W1T/DOC; later pk

__device__ inline ushort f2b(float v) {
    __hip_bfloat16 b = __float2bfloat16(v);
    return *(ushort*)&b;
}
__device__ inline float b2f(ushort u) {
    __hip_bfloat16 b = *(__hip_bfloat16*)&u;
    return __bfloat162float(b);
}

// ---------- fused pre-pass: head scores | P4 | doc split ----------
__global__ __launch_bounds__(256) void k_pre(const float* __restrict__ doc,
                                             const float* __restrict__ wh,
                                             const float* __restrict__ bh,
                                             float* __restrict__ hs,
                                             const float* __restrict__ wwe,
                                             const float* __restrict__ W1,
                                             float* __restrict__ P4,
                                             ushort* __restrict__ DOCH,
                                             ushort* __restrict__ DOCL) {
    int b = blockIdx.x;
    if (b < 256) {                                    // head: 4 words/block
        int wid = threadIdx.x >> 6, lane = threadIdx.x & 63;
        int word = b * 4 + wid;
        const float* row = doc + word * D;
        float acc = 0.f;
        for (int d = lane; d < D; d += 64) acc += row[d] * wh[d];
        #pragma unroll
        for (int o = 32; o; o >>= 1) acc += __shfl_down(acc, o);
        if (lane == 0) hs[word] = acc + bh[0];
    } else if (b < 256 + 118) {                       // P4
        int o = (b - 256) * 256 + threadIdx.x;
        if (o >= 30 * FFNN) return;
        int wi = o / FFNN, j = o - wi * FFNN;
        float acc = 0.f;
        #pragma unroll
        for (int f = 0; f < FEAT; ++f) acc += wwe[wi * FEAT + f] * W1[(1536 + f) * FFNN + j];
        P4[o] = acc;
    } else {                                          // doc split
        int i = (b - 374) * 256 + threadIdx.x;
        if (i >= NW * D) return;
        float v = doc[i];
        ushort hi = f2b(v);
        float r = v - b2f(hi);
        DOCH[i] = hi;
        DOCL[i] = f2b(r);
    }
}

// ---------- W1 slices: transpose + split -> W1T[z][1024 n][768 k] hi/lo ----------
__global__ void k_tw1(const float* __restrict__ W1,
                      ushort* __restrict__ TH, ushort* __restrict__ TL) {
    __shared__ float tile[32][33];
    int tx = threadIdx.x, ty = threadIdx.y;
    int k0 = blockIdx.x * 32, n0 = blockIdx.y * 32, z = blockIdx.z;
    int roff = (z == 0) ? 0 : (z == 1) ? 768 : 1556;
    #pragma unroll
    for (int i = 0; i < 4; ++i) {
        int kk = ty + i * 8;
        float v = (n0 + tx < FFNN) ? W1[(size_t)(roff + k0 + kk) * FFNN + n0 + tx] : 0.f;
        tile[kk][tx] = v;
    }
    __syncthreads();
    #pragma unroll
    for (int i = 0; i < 4; ++i) {
        int nn = ty + i * 8;
        float v = tile[tx][nn];
        ushort hi = f2b(v);
        float r = v - b2f(hi);
        size_t o = (size_t)z * 1024 * D + (size_t)(n0 + nn) * D + k0 + tx;
        TH[o] = hi;
        TL[o] = f2b(r);
    }
}

// ---------- W2: transpose + split -> W2T[1024 n][1024 k] hi/lo, zero-padded k ----------
__global__ void k_tw2(const float* __restrict__ W2,
                      ushort* __restrict__ TH, ushort* __restrict__ TL) {
    __shared__ float tile[32][33];
    int tx = threadIdx.x, ty = threadIdx.y;
    int k0 = blockIdx.x * 32, n0 = blockIdx.y * 32;
    #pragma unroll
    for (int i = 0; i < 4; ++i) {
        int kk = ty + i * 8;
        float v = (k0 + kk < FFNN && n0 + tx < FFNN)
                    ? W2[(size_t)(k0 + kk) * FFNN + n0 + tx] : 0.f;
        tile[kk][tx] = v;
    }
    __syncthreads();
    #pragma unroll
    for (int i = 0; i < 4; ++i) {
        int nn = ty + i * 8;
        int k = k0 + tx;
        float v = tile[tx][nn];
        ushort hi = f2b(v);
        float r = v - b2f(hi);
        size_t o = (size_t)(n0 + nn) * 1024 + k;
        TH[o] = hi;
        TL[o] = f2b(r);
    }
}

// ---------- perm rank: PRANK[i] = #{j : (starts[j], j) < (starts[i], i)} ----------
__global__ __launch_bounds__(256) void k_permA(const int* __restrict__ starts,
                                               int* __restrict__ PRANK) {
    __shared__ int ts[256];
    int i = blockIdx.x * 256 + threadIdx.x;
    int j = blockIdx.y * 256 + threadIdx.x;
    ts[threadIdx.x] = starts[j];
    __syncthreads();
    int si = starts[i];
    int jbase = blockIdx.y * 256;
    int r = 0;
    #pragma unroll 8
    for (int q = 0; q < 256; ++q) {
        int sj = ts[q];
        int jj = jbase + q;
        r += (sj < si) || ((sj == si) & (jj < i));
    }
    if (r) atomicAdd(&PRANK[i], r);
}

__global__ __launch_bounds__(256) void k_permB(const int* __restrict__ PRANK,
                                               int* __restrict__ PERM) {
    int i = blockIdx.x * 256 + threadIdx.x;
    PERM[PRANK[i]] = i;
}

// ---------- MFMA GEMM: P[z] = doc @ W1slice  (128x64 tile, 384 blocks, dbuf+lds-direct) ----------
__global__ __launch_bounds__(256) void k_gemmPm(const ushort* __restrict__ Ah_g,
                                                const ushort* __restrict__ Al_g,
                                                const ushort* __restrict__ Bh_g,
                                                const ushort* __restrict__ Bl_g,
                                                float* __restrict__ Pout) {
    __shared__ ushort LDS[2][12288];
    int tid = threadIdx.x;
    int orig = blockIdx.x;                    // 384 = 8 XCD * 48
    int t = (orig & 7) * 48 + (orig >> 3);
    int pair = t >> 4, colt = t & 15;
    int z = pair >> 3, rowt = pair & 7;
    int row0 = rowt * 128, col0 = colt * 64;
    size_t zoff = (size_t)z * 1024 * D;
    const ushort* Bh_z = Bh_g + zoff;
    const ushort* Bl_z = Bl_g + zoff;
    float* C = Pout + (size_t)z * NW * FFNN;
    int w = tid >> 6, l = tid & 63;
    int wr = w >> 1, wc = w & 1;
    int fr = l & 15, kb = l >> 4;
    int rA = tid >> 2, p = tid & 3;
    int q = p ^ ((rA >> 1) & 3);
    f32x4 acc[4][2] = {};
    int cur = 0;
    #define STAGE_P(d, kt)                                                                  \
        do {                                                                                \
            int kg = (kt) + q * 8;                                                          \
            __builtin_amdgcn_global_load_lds((const uint*)(Ah_g + (size_t)(row0 + rA) * D + kg),      (uint*)&LDS[d][(0 * 256 + tid) * 8], 16, 0, 0); \
            __builtin_amdgcn_global_load_lds((const uint*)(Ah_g + (size_t)(row0 + rA + 64) * D + kg), (uint*)&LDS[d][(1 * 256 + tid) * 8], 16, 0, 0); \
            __builtin_amdgcn_global_load_lds((const uint*)(Al_g + (size_t)(row0 + rA) * D + kg),      (uint*)&LDS[d][(2 * 256 + tid) * 8], 16, 0, 0); \
            __builtin_amdgcn_global_load_lds((const uint*)(Al_g + (size_t)(row0 + rA + 64) * D + kg), (uint*)&LDS[d][(3 * 256 + tid) * 8], 16, 0, 0); \
            __builtin_amdgcn_global_load_lds((const uint*)(Bh_z + (size_t)(col0 + rA) * D + kg),      (uint*)&LDS[d][(4 * 256 + tid) * 8], 16, 0, 0); \
            __builtin_amdgcn_global_load_lds((const uint*)(Bl_z + (size_t)(col0 + rA) * D + kg),      (uint*)&LDS[d][(5 * 256 + tid) * 8], 16, 0, 0); \
        } while (0)
    STAGE_P(0, 0);
    __syncthreads();
    for (int kt = 0; kt < D; kt += 32) {
        if (kt + 32 < D) STAGE_P(cur ^ 1, kt + 32);
        bf16x8 af[4], alf[4], bfr[2], blf[2];
        #pragma unroll
        for (int mt = 0; mt < 4; ++mt) {
            int r = wr * 64 + mt * 16 + fr;
            int sl = (kb ^ ((r >> 1) & 3)) * 8;
            af[mt]  = *(const bf16x8*)&LDS[cur][r * 32 + sl];
            alf[mt] = *(const bf16x8*)&LDS[cur][4096 + r * 32 + sl];
        }
        #pragma unroll
        for (int nt = 0; nt < 2; ++nt) {
            int c = wc * 32 + nt * 16 + fr;
            int sl = (kb ^ ((c >> 1) & 3)) * 8;
            bfr[nt] = *(const bf16x8*)&LDS[cur][8192 + c * 32 + sl];
            blf[nt] = *(const bf16x8*)&LDS[cur][10240 + c * 32 + sl];
        }
        #pragma unroll
        for (int mt = 0; mt < 4; ++mt)
            #pragma unroll
            for (int nt = 0; nt < 2; ++nt) {
                acc[mt][nt] = MFMA16(af[mt], bfr[nt], acc[mt][nt], 0, 0, 0);
                acc[mt][nt] = MFMA16(af[mt], blf[nt], acc[mt][nt], 0, 0, 0);
                acc[mt][nt] = MFMA16(alf[mt], bfr[nt], acc[mt][nt], 0, 0, 0);
            }
        __syncthreads();
        cur ^= 1;
    }
    #pragma unroll
    for (int mt = 0; mt < 4; ++mt)
        #pragma unroll
        for (int nt = 0; nt < 2; ++nt)
            #pragma unroll
            for (int r = 0; r < 4; ++r) {
                int row = row0 + wr * 64 + mt * 16 + kb * 4 + r;
                int col = col0 + wc * 32 + nt * 16 + fr;
                if (col < FFNN) C[(size_t)row * FFNN + col] = acc[mt][nt][r];
            }
}

// ---------- MFMA GEMM2 fused: relu(H1@W2+b2).W3 -> PS (dbuf + global_load_lds) ----------
__global__ __launch_bounds__(256) void k_gemm2m(const ushort* __restrict__ Ah_g,
                                                const ushort* __restrict__ Al_g,
                                                const ushort* __restrict__ Bh_g,
                                                const ushort* __restrict__ Bl_g,
                                                const float* __restrict__ b2,
                                                const float* __restrict__ W3,
                                                float* __restrict__ PS) {
    __shared__ ushort LDS[2][4][128 * 32];
    int tid = threadIdx.x;
    int orig = blockIdx.x;                    // 512 = 8 XCD * 64; XCD owns 8-row band
    int xcd = orig & 7, idx = orig >> 3;
    int rowt = xcd * 8 + (idx & 7), colt = idx >> 3;
    int row0 = rowt * 128, col0 = colt * 128;
    int w = tid >> 6, l = tid & 63;
    int wr = w >> 1, wc = w & 1;
    int fr = l & 15, kb = l >> 4;
    int r0 = tid >> 2, p = tid & 3;
    int r1 = r0 + 64;
    int q0 = p ^ ((r0 >> 1) & 3);
    int q1 = p ^ ((r1 >> 1) & 3);
    int base0 = (w * 64) * 8;
    int base1 = (256 + w * 64) * 8;
    f32x4 acc[4][4] = {};
    int cur = 0;
    #define STAGE_2(d, kt)                                                                  \
        do {                                                                                \
            int kg0 = (kt) + q0 * 8, kg1 = (kt) + q1 * 8;                                   \
            __builtin_amdgcn_global_load_lds((const uint*)(Ah_g + (size_t)(row0 + r0) * 1000 + kg0), (uint*)&LDS[d][0][base0], 16, 0, 0); \
            __builtin_amdgcn_global_load_lds((const uint*)(Al_g + (size_t)(row0 + r0) * 1000 + kg0), (uint*)&LDS[d][1][base0], 16, 0, 0); \
            __builtin_amdgcn_global_load_lds((const uint*)(Bh_g + (size_t)(col0 + r0) * 1024 + kg0), (uint*)&LDS[d][2][base0], 16, 0, 0); \
            __builtin_amdgcn_global_load_lds((const uint*)(Bl_g + (size_t)(col0 + r0) * 1024 + kg0), (uint*)&LDS[d][3][base0], 16, 0, 0); \
            __builtin_amdgcn_global_load_lds((const uint*)(Ah_g + (size_t)(row0 + r1) * 1000 + kg1), (uint*)&LDS[d][0][base1], 16, 0, 0); \
            __builtin_amdgcn_global_load_lds((const uint*)(Al_g + (size_t)(row0 + r1) * 1000 + kg1), (uint*)&LDS[d][1][base1], 16, 0, 0); \
            __builtin_amdgcn_global_load_lds((const uint*)(Bh_g + (size_t)(col0 + r1) * 1024 + kg1), (uint*)&LDS[d][2][base1], 16, 0, 0); \
            __builtin_amdgcn_global_load_lds((const uint*)(Bl_g + (size_t)(col0 + r1) * 1024 + kg1), (uint*)&LDS[d][3][base1], 16, 0, 0); \
        } while (0)
    STAGE_2(0, 0);
    __syncthreads();
    for (int kt = 0; kt < 1024; kt += 32) {
        if (kt + 32 < 1024) STAGE_2(cur ^ 1, kt + 32);
        bf16x8 af[4], alf[4], bfr[4], blf[4];
        #pragma unroll
        for (int mt = 0; mt < 4; ++mt) {
            int r = wr * 64 + mt * 16 + fr;
            int sl = (kb ^ ((r >> 1) & 3)) * 8;
            af[mt]  = *(const bf16x8*)&LDS[cur][0][r * 32 + sl];
            alf[mt] = *(const bf16x8*)&LDS[cur][1][r * 32 + sl];
        }
        #pragma unroll
        for (int nt = 0; nt < 4; ++nt) {
            int c = wc * 64 + nt * 16 + fr;
            int sl = (kb ^ ((c >> 1) & 3)) * 8;
            bfr[nt] = *(const bf16x8*)&LDS[cur][2][c * 32 + sl];
            blf[nt] = *(const bf16x8*)&LDS[cur][3][c * 32 + sl];
        }
        #pragma unroll
        for (int mt = 0; mt < 4; ++mt)
            #pragma unroll
            for (int nt = 0; nt < 4; ++nt) {
                acc[mt][nt] = MFMA16(af[mt], bfr[nt], acc[mt][nt], 0, 0, 0);
                acc[mt][nt] = MFMA16(af[mt], blf[nt], acc[mt][nt], 0, 0, 0);
                acc[mt][nt] = MFMA16(alf[mt], bfr[nt], acc[mt][nt], 0, 0, 0);
            }
        __syncthreads();
        cur ^= 1;
    }
    float w3v[4], b2v[4];
    #pragma unroll
    for (int nt = 0; nt < 4; ++nt) {
        int col = col0 + wc * 64 + nt * 16 + fr;
        bool cv = col < FFNN;
        w3v[nt] = cv ? W3[col] : 0.f;
        b2v[nt] = cv ? b2[col] : 0.f;
    }
    #pragma unroll
    for (int mt = 0; mt < 4; ++mt) {
        #pragma unroll
        for (int r = 0; r < 4; ++r) {
            float pp = 0.f;
            #pragma unroll
            for (int nt = 0; nt < 4; ++nt) {
                float v = fmaxf(acc[mt][nt][r] + b2v[nt], 0.f);
                pp = fmaf(v, w3v[nt], pp);
            }
            pp += __shfl_xor(pp, 1);
            pp += __shfl_xor(pp, 2);
            pp += __shfl_xor(pp, 4);
            pp += __shfl_xor(pp, 8);
            if (fr == 0) {
                int row = row0 + wr * 64 + mt * 16 + kb * 4 + r;
                PS[row * 16 + colt * 2 + wc] = pp;
            }
        }
    }
}

// ---------- h1 assembly (start-sorted via PERM, XCD-chunked): softmax + gather + relu -> bf16 hi/lo ----------
__global__ __launch_bounds__(256) void k_h1(const float* __restrict__ P,
                                            const float* __restrict__ P4,
                                            const float* __restrict__ hs,
                                            const float* __restrict__ b1,
                                            const int* __restrict__ starts,
                                            const int* __restrict__ ends,
                                            const int* __restrict__ PERM,
                                            ushort* __restrict__ H1h,
                                            ushort* __restrict__ H1l) {
    __shared__ float shs[32];
    int bid = blockIdx.x;
    int i = ((bid & 7) << 10) | (bid >> 3);   // XCD-contiguous sorted position
    int tid = threadIdx.x;
    int span = PERM[i];                        // uniform broadcast load
    int st = starts[span], en = ends[span];
    int width = en - st + 1;
    if (tid < MAXW) {
        int idx = st + tid; if (idx > NW - 1) idx = NW - 1;
        shs[tid] = hs[idx];
    }
    __syncthreads();
    float v[MAXW];
    float mx = -3.0e38f;
    #pragma unroll
    for (int w = 0; w < MAXW; ++w) {
        float x = shs[w];
        v[w] = (w < width) ? x : -3.0e38f;
        mx = fmaxf(mx, v[w]);
    }
    float sum = 0.f;
    #pragma unroll
    for (int w = 0; w < MAXW; ++w) { v[w] = expf(v[w] - mx); sum += v[w]; }
    float inv = 1.f / sum;
    if (tid >= 250) return;
    const float4* P1r = (const float4*)(P + (size_t)st * FFNN);
    const float4* P2r = (const float4*)(P + (size_t)NW * FFNN + (size_t)en * FFNN);
    const float*  P3  = P + 2 * (size_t)NW * FFNN;
    const float4* P4r = (const float4*)(P4 + (size_t)(width - 1) * FFNN);
    const float4* b1v = (const float4*)b1;
    float4 a = P1r[tid], b = P2r[tid], c = P4r[tid], d = b1v[tid];
    float4 acc = {a.x + b.x + c.x + d.x,
                  a.y + b.y + c.y + d.y,
                  a.z + b.z + c.z + d.z,
                  a.w + b.w + c.w + d.w};
    for (int w = 0; w < width; ++w) {
        float aw = v[w] * inv;
        float4 p3 = ((const float4*)(P3 + (size_t)(st + w) * FFNN))[tid];
        acc.x = fmaf(aw, p3.x, acc.x);
        acc.y = fmaf(aw, p3.y, acc.y);
        acc.z = fmaf(aw, p3.z, acc.z);
        acc.w = fmaf(aw, p3.w, acc.w);
    }
    float rv[4] = {fmaxf(acc.x, 0.f), fmaxf(acc.y, 0.f), fmaxf(acc.z, 0.f), fmaxf(acc.w, 0.f)};
    ushort4 hi, lo;
    ushort* hp = (ushort*)&hi;
    ushort* lp = (ushort*)&lo;
    #pragma unroll
    for (int j = 0; j < 4; ++j) {
        ushort h = f2b(rv[j]);
        float r = rv[j] - b2f(h);
        hp[j] = h;
        lp[j] = f2b(r);
    }
    *(ushort4*)(H1h + (size_t)i * FFNN + tid * 4) = hi;
    *(ushort4*)(H1l + (size_t)i * FFNN + tid * 4) = lo;
}

// ---------- final score: sum 16 partials + b3, scatter back to span order ----------
__global__ __launch_bounds__(256) void k_score2(const float* __restrict__ PS,
                                                const float* __restrict__ b3,
                                                const int* __restrict__ PERM,
                                                float* __restrict__ out) {
    int r = blockIdx.x * 256 + threadIdx.x;
    if (r >= NS) return;
    float s = 0.f;
    #pragma unroll
    for (int b = 0; b < 16; ++b) s += PS[r * 16 + b];
    out[PERM[r]] = s + b3[0];
}

// ---------- tile-parallel rank ----------
__global__ __launch_bounds__(256) void k_rankA(const float* __restrict__ scores,
                                               int* __restrict__ RANK) {
    __shared__ unsigned long long tile[256];
    int i = blockIdx.x * 256 + threadIdx.x;
    int j = blockIdx.y * 256 + threadIdx.x;
    unsigned uj = __float_as_uint(scores[j]);
    unsigned mj = (uj >> 31) ? ~uj : (uj | 0x80000000u);
    tile[threadIdx.x] = ((unsigned long long)(~mj) << 32) | (unsigned)j;
    __syncthreads();
    unsigned u = __float_as_uint(scores[i]);
    unsigned m = (u >> 31) ? ~u : (u | 0x80000000u);
    unsigned long long key = ((unsigned long long)(~m) << 32) | (unsigned)i;
    int r = 0;
    #pragma unroll 8
    for (int q = 0; q < 256; ++q) r += (tile[q] < key);
    if (r) atomicAdd(&RANK[i], r);
}

// ---------- scatter: pk[RANK[i]] = packed (span, start, end) ----------
__global__ __launch_bounds__(256) void k_rankB(const int* __restrict__ RANK,
                                               const int* __restrict__ starts,
                                               const int* __restrict__ ends,
                                               unsigned long long* __restrict__ pk) {
    int i = blockIdx.x * 256 + threadIdx.x;
    pk[RANK[i]] = ((unsigned long long)(unsigned)i << 32) |
                  ((unsigned)starts[i] << 16) | (unsigned)ends[i];
}

// ---------- parallel pairwise-mask precompute ----------
__global__ __launch_bounds__(64) void k_masks(const unsigned long long* __restrict__ pk,
                                              unsigned long long* __restrict__ MC,
                                              unsigned long long* __restrict__ ME,
                                              unsigned long long* __restrict__ MG) {
    int lane = threadIdx.x;
    int c = blockIdx.x;
    unsigned long long p = pk[c * 64 + lane];
    int s = (int)((p >> 16) & 0xFFFF);
    int e = (int)(p & 0xFFFF);
    unsigned long long conf = 0, eqm = 0, gtm = 0;
    for (int r = 1; r < 64; ++r) {
        int j = (lane + r) & 63;
        int sj = __shfl(s, j);
        int ej = __shfl(e, j);
        unsigned long long bit = 1ull << j;
        bool cross = ((sj > s) & (sj <= e) & (ej > e)) |
                     ((ej >= s) & (ej < e) & (sj < s));
        if (cross) conf |= bit;
        if (sj == s) { if (ej == e) eqm |= bit; else if (ej > e) gtm |= bit; }
    }
    MC[c * 64 + lane] = conf;
    ME[c * 64 + lane] = eqm;
    MG[c * 64 + lane] = gtm;
}

// ---------- greedy crossing-suppression scan (masks precomputed) ----------
__global__ __launch_bounds__(64) void k_scan(const unsigned long long* __restrict__ pk,
                                             const unsigned long long* __restrict__ MC,
                                             const unsigned long long* __restrict__ ME,
                                             const unsigned long long* __restrict__ MG,
                                             int top, int* __restrict__ SEL,
                                             int* __restrict__ SELKEY,
                                             int* __restrict__ CNT) {
    __shared__ int mxs[NW];
    __shared__ int mne[NW];
    __shared__ int mxe[NW];
    int lane = threadIdx.x;
    unsigned long long lower = (1ull << lane) - 1ull;
    for (int p = lane; p < NW; p += 64) { mxs[p] = -1; mne[p] = NW; mxe[p] = -1; }
    __syncthreads();
    int count = 0;
    unsigned long long pc = pk[lane];
    unsigned long long conf = MC[lane], eqm = ME[lane], gtm = MG[lane];
    for (int c = 0; c < NS / 64 && count < top; ++c) {
        unsigned long long pn = 0, cn = 0, en2 = 0, gn = 0;
        if (c + 1 < NS / 64) {
            int o = (c + 1) * 64 + lane;
            pn = pk[o]; cn = MC[o]; en2 = ME[o]; gn = MG[o];
        }
        int span = (int)(pc >> 32);
        int s = (int)((pc >> 16) & 0xFFFF);
        int e = (int)(pc & 0xFFFF);
        int bad = (mxs[e] > s) | (mne[s] < e);
        int g = mxe[s];
        bool gdup = (g == e), ggt = (g > e);
        unsigned long long pending = __ballot(!bad), committed = 0;
        unsigned long long relv = (conf | eqm | gtm) & lower;
        while (pending) {
            bool mine = (pending >> lane) & 1;
            bool ready = mine && ((pending & relv) == 0ull);
            unsigned long long cb = committed & lower;
            bool rej = (cb & conf) != 0ull;
            bool gt_any = ggt || ((cb & gtm) != 0ull);
            bool eq_any = gdup || ((cb & eqm) != 0ull);
            bool acc_now = ready && !rej && !(eq_any && !gt_any);
            committed |= __ballot(acc_now);
            pending &= ~__ballot(ready);
        }
        int allowed = top - count;
        while (__popcll(committed) > allowed)
            committed &= ~(1ull << (63 - __builtin_clzll(committed)));
        if ((committed >> lane) & 1) {
            int pos = count + __popcll(committed & lower);
            SEL[pos] = span;
            SELKEY[pos] = s * NW + e;
            atomicMax(&mxe[s], e);
            #pragma unroll
            for (int k = 0; k < MAXW - 1; ++k) {
                if (k < e - s) {
                    atomicMax(&mxs[s + k], s);
                    atomicMin(&mne[s + 1 + k], e);
                }
            }
        }
        count += __popcll(committed);
        __syncthreads();
        pc = pn; conf = cn; eqm = en2; gtm = gn;
    }
    if (lane == 0) *CNT = count;
}

// ---------- final sort: multi-wave rank sort of the selected spans ----------
__global__ __launch_bounds__(512) void k_sort(const int* __restrict__ SEL,
                                              const int* __restrict__ SELKEY,
                                              const int* __restrict__ CNT,
                                              int top, float* __restrict__ out_idx) {
    __shared__ int keys[512];
    __shared__ int vals[512];
    int cnt = *CNT;
    int r = threadIdx.x;
    if (r < top) {
        keys[r] = (r < cnt) ? SELKEY[r] : NW * NW;
        vals[r] = (r < cnt) ? SEL[r] : -1;
    }
    __syncthreads();
    if (r < top) {
        int kr = keys[r];
        int rank = 0;
        for (int q = 0; q < top; ++q) {
            int kq = keys[q];
            rank += (kq < kr) || (kq == kr && q < r);
        }
        out_idx[rank] = (float)vals[r];
    }
}

extern "C" void kernel_launch(void* const* d_in, const int* in_sizes, int n_in,
                              void* d_out, int out_size, void* d_ws, size_t ws_size,
                              hipStream_t stream) {
    const float* doc = (const float*)d_in[0];
    const float* wwe = (const float*)d_in[1];
    const float* wh  = (const float*)d_in[2];
    const float* bh  = (const float*)d_in[3];
    const float* W1  = (const float*)d_in[4];
    const float* b1  = (const float*)d_in[5];
    const float* W2  = (const float*)d_in[6];
    const float* b2  = (const float*)d_in[7];
    const float* W3  = (const float*)d_in[8];
    const float* b3  = (const float*)d_in[9];
    const int* starts = (const int*)d_in[10];
    const int* ends   = (const int*)d_in[11];
    int top = out_size - NS;                 // 409

    float* ws  = (float*)d_ws;
    float* P   = ws + O_P;
    float* P4  = ws + O_P4;
    float* HS  = ws + O_HS;
    float* PS  = ws + O_PS;
    float* H1R = ws + O_H1R;
    ushort* H1H = (ushort*)H1R;
    ushort* H1L = (ushort*)(H1R + 4096000);
    ushort* W1TH = (ushort*)H1R;
    ushort* W1TL = (ushort*)(H1R + 1179648);
    ushort* DOCH = (ushort*)(H1R + 2359296);
    ushort* DOCL = (ushort*)(H1R + 2752512);
    ushort* W2TH = (ushort*)ws;                          // 1024*1024 ushorts
    ushort* W2TL = (ushort*)(ws + 524288);
    unsigned long long* PK = (unsigned long long*)H1R;   // dead after k_gemm2m
    int* SEL    = (int*)(ws + O_ATT);
    int* SELKEY = SEL + 512;
    int* CNT    = SEL + 1024;
    int* PRANK  = SEL + 2048;                            // 8192 ints
    int* RANK   = SEL + 2048 + 8192;                     // 8192 ints (zeroed together)
    int* PERM   = SEL + 2048 + 16384;                    // 8192 ints
    unsigned long long* MC = (unsigned long long*)(ws + O_PS);   // PS dead after k_score2
    unsigned long long* ME = MC + NS;
    unsigned long long* MG = MC + 2 * NS;
    float* outs = (float*)d_out;

    hipMemsetAsync(PRANK, 0, 2 * NS * sizeof(int), stream);   // PRANK + RANK

    k_pre<<<3446, 256, 0, stream>>>(doc, wh, bh, HS, wwe, W1, P4, DOCH, DOCL);
    {
        dim3 g(24, 32, 3), b(32, 8);
        k_tw1<<<g, b, 0, stream>>>(W1, W1TH, W1TL);
    }
    {
        dim3 g(NS / 256, NS / 256);
        k_permA<<<g, 256, 0, stream>>>(starts, PRANK);
    }
    k_permB<<<NS / 256, 256, 0, stream>>>(PRANK, PERM);

    k_gemmPm<<<384, 256, 0, stream>>>(DOCH, DOCL, W1TH, W1TL, P);

    k_h1<<<NS, 256, 0, stream>>>(P, P4, HS, b1, starts, ends, PERM, H1H, H1L);

    {
        dim3 g(32, 32), b(32, 8);
        k_tw2<<<g, b, 0, stream>>>(W2, W2TH, W2TL);
    }
    k_gemm2m<<<512, 256, 0, stream>>>(H1H, H1L, W2TH, W2TL, b2, W3, PS);

    k_score2<<<NS / 256, 256, 0, stream>>>(PS, b3, PERM, outs);

    {
        dim3 g(NS / 256, NS / 256);
        k_rankA<<<g, 256, 0, stream>>>(outs, RANK);
    }
    k_rankB<<<NS / 256, 256, 0, stream>>>(RANK, starts, ends, PK);
    k_masks<<<NS / 64, 64, 0, stream>>>(PK, MC, ME, MG);
    k_scan<<<1, 64, 0, stream>>>(PK, MC, ME, MG, top, SEL, SELKEY, CNT);
    k_sort<<<1, 512, 0, stream>>>(SEL, SELKEY, CNT, top, outs + NS);
}

// Round 15
// 224.336 us; speedup vs baseline: 1.0634x; 1.0634x over previous
//
#include <hip/hip_runtime.h>
#include <hip/hip_bf16.h>
#include <stdint.h>

#define NW   1024
#define D    768
#define NS   8192
#define MAXW 30
#define FFNN 1000
#define FEAT 20

typedef __attribute__((ext_vector_type(8))) short bf16x8;
typedef __attribute__((ext_vector_type(4))) float f32x4;
#define MFMA16 __builtin_amdgcn_mfma_f32_16x16x32_bf16

// ws layout (float-slot offsets)
#define O_P    0                          // 3*1024*1000 fp32 P1,P2,P3 (later W2T 1024-stride)
#define O_P4   3072000                    // 30*1000
#define O_HS   3102000                    // 1024
#define O_ATT  3103024                    // SEL/SELKEY/CNT/RANK region
#define O_PS   3365168                    // 8192*16 (PS; later MC/ME/MG masks)
#define O_H1R  3504432                    // H1 hi/lo bf16; earlier W1T/DOC aliases; later pk

__device__ inline ushort f2b(float v) {
    __hip_bfloat16 b = __float2bfloat16(v);
    return *(ushort*)&b;
}
__device__ inline float b2f(ushort u) {
    __hip_bfloat16 b = *(__hip_bfloat16*)&u;
    return __bfloat162float(b);
}

// ---------- fused pre-pass: head | P4 | doc split | W1 transpose+split ----------
__global__ __launch_bounds__(256) void k_pre(const float* __restrict__ doc,
                                             const float* __restrict__ wh,
                                             const float* __restrict__ bh,
                                             float* __restrict__ hs,
                                             const float* __restrict__ wwe,
                                             const float* __restrict__ W1,
                                             float* __restrict__ P4,
                                             ushort* __restrict__ DOCH,
                                             ushort* __restrict__ DOCL,
                                             ushort* __restrict__ W1TH,
                                             ushort* __restrict__ W1TL) {
    __shared__ float tile[32][33];
    int b = blockIdx.x;
    int tid = threadIdx.x;
    if (b < 256) {                                    // head: 4 words/block
        int wid = tid >> 6, lane = tid & 63;
        int word = b * 4 + wid;
        const float* row = doc + word * D;
        float acc = 0.f;
        for (int d = lane; d < D; d += 64) acc += row[d] * wh[d];
        #pragma unroll
        for (int o = 32; o; o >>= 1) acc += __shfl_down(acc, o);
        if (lane == 0) hs[word] = acc + bh[0];
    } else if (b < 374) {                             // P4
        int o = (b - 256) * 256 + tid;
        if (o >= 30 * FFNN) return;
        int wi = o / FFNN, j = o - wi * FFNN;
        float acc = 0.f;
        #pragma unroll
        for (int f = 0; f < FEAT; ++f) acc += wwe[wi * FEAT + f] * W1[(1536 + f) * FFNN + j];
        P4[o] = acc;
    } else if (b < 3446) {                            // doc split
        int i = (b - 374) * 256 + tid;
        if (i >= NW * D) return;
        float v = doc[i];
        ushort hi = f2b(v);
        float r = v - b2f(hi);
        DOCH[i] = hi;
        DOCL[i] = f2b(r);
    } else {                                          // W1 transpose+split (2304 blocks)
        int lb = b - 3446;
        int z = lb / 768, rem = lb - z * 768;
        int ny = rem / 24, kx = rem - ny * 24;
        int k0 = kx * 32, n0 = ny * 32;
        int tx = tid & 31, ty = tid >> 5;
        int roff = (z == 0) ? 0 : (z == 1) ? 768 : 1556;
        #pragma unroll
        for (int i = 0; i < 4; ++i) {
            int kk = ty + i * 8;
            float v = (n0 + tx < FFNN) ? W1[(size_t)(roff + k0 + kk) * FFNN + n0 + tx] : 0.f;
            tile[kk][tx] = v;
        }
        __syncthreads();
        #pragma unroll
        for (int i = 0; i < 4; ++i) {
            int nn = ty + i * 8;
            float v = tile[tx][nn];
            ushort hi = f2b(v);
            float r = v - b2f(hi);
            size_t o = (size_t)z * 1024 * D + (size_t)(n0 + nn) * D + k0 + tx;
            W1TH[o] = hi;
            W1TL[o] = f2b(r);
        }
    }
}

// ---------- W2: transpose + split -> W2T[1024 n][1024 k] hi/lo, zero-padded k ----------
__global__ void k_tw2(const float* __restrict__ W2,
                      ushort* __restrict__ TH, ushort* __restrict__ TL) {
    __shared__ float tile[32][33];
    int tx = threadIdx.x, ty = threadIdx.y;
    int k0 = blockIdx.x * 32, n0 = blockIdx.y * 32;
    #pragma unroll
    for (int i = 0; i < 4; ++i) {
        int kk = ty + i * 8;
        float v = (k0 + kk < FFNN && n0 + tx < FFNN)
                    ? W2[(size_t)(k0 + kk) * FFNN + n0 + tx] : 0.f;
        tile[kk][tx] = v;
    }
    __syncthreads();
    #pragma unroll
    for (int i = 0; i < 4; ++i) {
        int nn = ty + i * 8;
        int k = k0 + tx;
        float v = tile[tx][nn];
        ushort hi = f2b(v);
        float r = v - b2f(hi);
        size_t o = (size_t)(n0 + nn) * 1024 + k;
        TH[o] = hi;
        TL[o] = f2b(r);
    }
}

// ---------- MFMA GEMM: P[z] = doc @ W1slice  (128x64 tile, 384 blocks, dbuf+lds-direct) ----------
__global__ __launch_bounds__(256) void k_gemmPm(const ushort* __restrict__ Ah_g,
                                                const ushort* __restrict__ Al_g,
                                                const ushort* __restrict__ Bh_g,
                                                const ushort* __restrict__ Bl_g,
                                                float* __restrict__ Pout) {
    __shared__ ushort LDS[2][12288];
    int tid = threadIdx.x;
    int orig = blockIdx.x;                    // 384 = 8 XCD * 48
    int t = (orig & 7) * 48 + (orig >> 3);
    int pair = t >> 4, colt = t & 15;
    int z = pair >> 3, rowt = pair & 7;
    int row0 = rowt * 128, col0 = colt * 64;
    size_t zoff = (size_t)z * 1024 * D;
    const ushort* Bh_z = Bh_g + zoff;
    const ushort* Bl_z = Bl_g + zoff;
    float* C = Pout + (size_t)z * NW * FFNN;
    int w = tid >> 6, l = tid & 63;
    int wr = w >> 1, wc = w & 1;
    int fr = l & 15, kb = l >> 4;
    int rA = tid >> 2, p = tid & 3;
    int q = p ^ ((rA >> 1) & 3);
    f32x4 acc[4][2] = {};
    int cur = 0;
    #define STAGE_P(d, kt)                                                                  \
        do {                                                                                \
            int kg = (kt) + q * 8;                                                          \
            __builtin_amdgcn_global_load_lds((const uint*)(Ah_g + (size_t)(row0 + rA) * D + kg),      (uint*)&LDS[d][(0 * 256 + tid) * 8], 16, 0, 0); \
            __builtin_amdgcn_global_load_lds((const uint*)(Ah_g + (size_t)(row0 + rA + 64) * D + kg), (uint*)&LDS[d][(1 * 256 + tid) * 8], 16, 0, 0); \
            __builtin_amdgcn_global_load_lds((const uint*)(Al_g + (size_t)(row0 + rA) * D + kg),      (uint*)&LDS[d][(2 * 256 + tid) * 8], 16, 0, 0); \
            __builtin_amdgcn_global_load_lds((const uint*)(Al_g + (size_t)(row0 + rA + 64) * D + kg), (uint*)&LDS[d][(3 * 256 + tid) * 8], 16, 0, 0); \
            __builtin_amdgcn_global_load_lds((const uint*)(Bh_z + (size_t)(col0 + rA) * D + kg),      (uint*)&LDS[d][(4 * 256 + tid) * 8], 16, 0, 0); \
            __builtin_amdgcn_global_load_lds((const uint*)(Bl_z + (size_t)(col0 + rA) * D + kg),      (uint*)&LDS[d][(5 * 256 + tid) * 8], 16, 0, 0); \
        } while (0)
    STAGE_P(0, 0);
    __syncthreads();
    for (int kt = 0; kt < D; kt += 32) {
        if (kt + 32 < D) STAGE_P(cur ^ 1, kt + 32);
        bf16x8 af[4], alf[4], bfr[2], blf[2];
        #pragma unroll
        for (int mt = 0; mt < 4; ++mt) {
            int r = wr * 64 + mt * 16 + fr;
            int sl = (kb ^ ((r >> 1) & 3)) * 8;
            af[mt]  = *(const bf16x8*)&LDS[cur][r * 32 + sl];
            alf[mt] = *(const bf16x8*)&LDS[cur][4096 + r * 32 + sl];
        }
        #pragma unroll
        for (int nt = 0; nt < 2; ++nt) {
            int c = wc * 32 + nt * 16 + fr;
            int sl = (kb ^ ((c >> 1) & 3)) * 8;
            bfr[nt] = *(const bf16x8*)&LDS[cur][8192 + c * 32 + sl];
            blf[nt] = *(const bf16x8*)&LDS[cur][10240 + c * 32 + sl];
        }
        #pragma unroll
        for (int mt = 0; mt < 4; ++mt)
            #pragma unroll
            for (int nt = 0; nt < 2; ++nt) {
                acc[mt][nt] = MFMA16(af[mt], bfr[nt], acc[mt][nt], 0, 0, 0);
                acc[mt][nt] = MFMA16(af[mt], blf[nt], acc[mt][nt], 0, 0, 0);
                acc[mt][nt] = MFMA16(alf[mt], bfr[nt], acc[mt][nt], 0, 0, 0);
            }
        __syncthreads();
        cur ^= 1;
    }
    #pragma unroll
    for (int mt = 0; mt < 4; ++mt)
        #pragma unroll
        for (int nt = 0; nt < 2; ++nt)
            #pragma unroll
            for (int r = 0; r < 4; ++r) {
                int row = row0 + wr * 64 + mt * 16 + kb * 4 + r;
                int col = col0 + wc * 32 + nt * 16 + fr;
                if (col < FFNN) C[(size_t)row * FFNN + col] = acc[mt][nt][r];
            }
}

// ---------- MFMA GEMM2 fused: relu(H1@W2+b2).W3 -> PS (dbuf + global_load_lds) ----------
__global__ __launch_bounds__(256) void k_gemm2m(const ushort* __restrict__ Ah_g,
                                                const ushort* __restrict__ Al_g,
                                                const ushort* __restrict__ Bh_g,
                                                const ushort* __restrict__ Bl_g,
                                                const float* __restrict__ b2,
                                                const float* __restrict__ W3,
                                                float* __restrict__ PS) {
    __shared__ ushort LDS[2][4][128 * 32];
    int tid = threadIdx.x;
    int orig = blockIdx.x;                    // 512 = 8 XCD * 64; XCD owns 8-row band
    int xcd = orig & 7, idx = orig >> 3;
    int rowt = xcd * 8 + (idx & 7), colt = idx >> 3;
    int row0 = rowt * 128, col0 = colt * 128;
    int w = tid >> 6, l = tid & 63;
    int wr = w >> 1, wc = w & 1;
    int fr = l & 15, kb = l >> 4;
    int r0 = tid >> 2, p = tid & 3;
    int r1 = r0 + 64;
    int q0 = p ^ ((r0 >> 1) & 3);
    int q1 = p ^ ((r1 >> 1) & 3);
    int base0 = (w * 64) * 8;
    int base1 = (256 + w * 64) * 8;
    f32x4 acc[4][4] = {};
    int cur = 0;
    #define STAGE_2(d, kt)                                                                  \
        do {                                                                                \
            int kg0 = (kt) + q0 * 8, kg1 = (kt) + q1 * 8;                                   \
            __builtin_amdgcn_global_load_lds((const uint*)(Ah_g + (size_t)(row0 + r0) * 1000 + kg0), (uint*)&LDS[d][0][base0], 16, 0, 0); \
            __builtin_amdgcn_global_load_lds((const uint*)(Al_g + (size_t)(row0 + r0) * 1000 + kg0), (uint*)&LDS[d][1][base0], 16, 0, 0); \
            __builtin_amdgcn_global_load_lds((const uint*)(Bh_g + (size_t)(col0 + r0) * 1024 + kg0), (uint*)&LDS[d][2][base0], 16, 0, 0); \
            __builtin_amdgcn_global_load_lds((const uint*)(Bl_g + (size_t)(col0 + r0) * 1024 + kg0), (uint*)&LDS[d][3][base0], 16, 0, 0); \
            __builtin_amdgcn_global_load_lds((const uint*)(Ah_g + (size_t)(row0 + r1) * 1000 + kg1), (uint*)&LDS[d][0][base1], 16, 0, 0); \
            __builtin_amdgcn_global_load_lds((const uint*)(Al_g + (size_t)(row0 + r1) * 1000 + kg1), (uint*)&LDS[d][1][base1], 16, 0, 0); \
            __builtin_amdgcn_global_load_lds((const uint*)(Bh_g + (size_t)(col0 + r1) * 1024 + kg1), (uint*)&LDS[d][2][base1], 16, 0, 0); \
            __builtin_amdgcn_global_load_lds((const uint*)(Bl_g + (size_t)(col0 + r1) * 1024 + kg1), (uint*)&LDS[d][3][base1], 16, 0, 0); \
        } while (0)
    STAGE_2(0, 0);
    __syncthreads();
    for (int kt = 0; kt < 1024; kt += 32) {
        if (kt + 32 < 1024) STAGE_2(cur ^ 1, kt + 32);
        bf16x8 af[4], alf[4], bfr[4], blf[4];
        #pragma unroll
        for (int mt = 0; mt < 4; ++mt) {
            int r = wr * 64 + mt * 16 + fr;
            int sl = (kb ^ ((r >> 1) & 3)) * 8;
            af[mt]  = *(const bf16x8*)&LDS[cur][0][r * 32 + sl];
            alf[mt] = *(const bf16x8*)&LDS[cur][1][r * 32 + sl];
        }
        #pragma unroll
        for (int nt = 0; nt < 4; ++nt) {
            int c = wc * 64 + nt * 16 + fr;
            int sl = (kb ^ ((c >> 1) & 3)) * 8;
            bfr[nt] = *(const bf16x8*)&LDS[cur][2][c * 32 + sl];
            blf[nt] = *(const bf16x8*)&LDS[cur][3][c * 32 + sl];
        }
        #pragma unroll
        for (int mt = 0; mt < 4; ++mt)
            #pragma unroll
            for (int nt = 0; nt < 4; ++nt) {
                acc[mt][nt] = MFMA16(af[mt], bfr[nt], acc[mt][nt], 0, 0, 0);
                acc[mt][nt] = MFMA16(af[mt], blf[nt], acc[mt][nt], 0, 0, 0);
                acc[mt][nt] = MFMA16(alf[mt], bfr[nt], acc[mt][nt], 0, 0, 0);
            }
        __syncthreads();
        cur ^= 1;
    }
    float w3v[4], b2v[4];
    #pragma unroll
    for (int nt = 0; nt < 4; ++nt) {
        int col = col0 + wc * 64 + nt * 16 + fr;
        bool cv = col < FFNN;
        w3v[nt] = cv ? W3[col] : 0.f;
        b2v[nt] = cv ? b2[col] : 0.f;
    }
    #pragma unroll
    for (int mt = 0; mt < 4; ++mt) {
        #pragma unroll
        for (int r = 0; r < 4; ++r) {
            float pp = 0.f;
            #pragma unroll
            for (int nt = 0; nt < 4; ++nt) {
                float v = fmaxf(acc[mt][nt][r] + b2v[nt], 0.f);
                pp = fmaf(v, w3v[nt], pp);
            }
            pp += __shfl_xor(pp, 1);
            pp += __shfl_xor(pp, 2);
            pp += __shfl_xor(pp, 4);
            pp += __shfl_xor(pp, 8);
            if (fr == 0) {
                int row = row0 + wr * 64 + mt * 16 + kb * 4 + r;
                PS[row * 16 + colt * 2 + wc] = pp;
            }
        }
    }
}

// ---------- h1 assembly (attn fused): softmax + gather P rows + bias + relu -> bf16 hi/lo ----------
__global__ __launch_bounds__(256) void k_h1(const float* __restrict__ P,
                                            const float* __restrict__ P4,
                                            const float* __restrict__ hs,
                                            const float* __restrict__ b1,
                                            const int* __restrict__ starts,
                                            const int* __restrict__ ends,
                                            ushort* __restrict__ H1h,
                                            ushort* __restrict__ H1l) {
    __shared__ float shs[32];
    int s = blockIdx.x;
    int tid = threadIdx.x;
    int st = starts[s], en = ends[s];
    int width = en - st + 1;
    if (tid < MAXW) {
        int idx = st + tid; if (idx > NW - 1) idx = NW - 1;
        shs[tid] = hs[idx];
    }
    __syncthreads();
    float v[MAXW];
    float mx = -3.0e38f;
    #pragma unroll
    for (int w = 0; w < MAXW; ++w) {
        float x = shs[w];
        v[w] = (w < width) ? x : -3.0e38f;
        mx = fmaxf(mx, v[w]);
    }
    float sum = 0.f;
    #pragma unroll
    for (int w = 0; w < MAXW; ++w) { v[w] = expf(v[w] - mx); sum += v[w]; }
    float inv = 1.f / sum;
    if (tid >= 250) return;
    const float4* P1r = (const float4*)(P + (size_t)st * FFNN);
    const float4* P2r = (const float4*)(P + (size_t)NW * FFNN + (size_t)en * FFNN);
    const float*  P3  = P + 2 * (size_t)NW * FFNN;
    const float4* P4r = (const float4*)(P4 + (size_t)(width - 1) * FFNN);
    const float4* b1v = (const float4*)b1;
    float4 a = P1r[tid], b = P2r[tid], c = P4r[tid], d = b1v[tid];
    float4 acc = {a.x + b.x + c.x + d.x,
                  a.y + b.y + c.y + d.y,
                  a.z + b.z + c.z + d.z,
                  a.w + b.w + c.w + d.w};
    for (int w = 0; w < width; ++w) {
        float aw = v[w] * inv;
        float4 p3 = ((const float4*)(P3 + (size_t)(st + w) * FFNN))[tid];
        acc.x = fmaf(aw, p3.x, acc.x);
        acc.y = fmaf(aw, p3.y, acc.y);
        acc.z = fmaf(aw, p3.z, acc.z);
        acc.w = fmaf(aw, p3.w, acc.w);
    }
    float rv[4] = {fmaxf(acc.x, 0.f), fmaxf(acc.y, 0.f), fmaxf(acc.z, 0.f), fmaxf(acc.w, 0.f)};
    ushort4 hi, lo;
    ushort* hp = (ushort*)&hi;
    ushort* lp = (ushort*)&lo;
    #pragma unroll
    for (int j = 0; j < 4; ++j) {
        ushort h = f2b(rv[j]);
        float r = rv[j] - b2f(h);
        hp[j] = h;
        lp[j] = f2b(r);
    }
    *(ushort4*)(H1h + (size_t)s * FFNN + tid * 4) = hi;
    *(ushort4*)(H1l + (size_t)s * FFNN + tid * 4) = lo;
}

// ---------- fused score + tile-parallel rank: out[i] (by==0) and RANK[i] += partial ----------
__global__ __launch_bounds__(256) void k_srank(const float* __restrict__ PS,
                                               const float* __restrict__ b3,
                                               float* __restrict__ out,
                                               int* __restrict__ RANK) {
    __shared__ unsigned long long tile[256];
    int i = blockIdx.x * 256 + threadIdx.x;
    int j = blockIdx.y * 256 + threadIdx.x;
    float b3v = b3[0];
    float sj = 0.f;
    #pragma unroll
    for (int b = 0; b < 16; ++b) sj += PS[j * 16 + b];
    sj += b3v;
    unsigned uj = __float_as_uint(sj);
    unsigned mj = (uj >> 31) ? ~uj : (uj | 0x80000000u);
    tile[threadIdx.x] = ((unsigned long long)(~mj) << 32) | (unsigned)j;
    float si = 0.f;
    #pragma unroll
    for (int b = 0; b < 16; ++b) si += PS[i * 16 + b];
    si += b3v;
    if (blockIdx.y == 0) out[i] = si;
    __syncthreads();
    unsigned u = __float_as_uint(si);
    unsigned m = (u >> 31) ? ~u : (u | 0x80000000u);
    unsigned long long key = ((unsigned long long)(~m) << 32) | (unsigned)i;
    int r = 0;
    #pragma unroll 8
    for (int q = 0; q < 256; ++q) r += (tile[q] < key);
    if (r) atomicAdd(&RANK[i], r);
}

// ---------- scatter: pk[RANK[i]] = packed (span, start, end) ----------
__global__ __launch_bounds__(256) void k_rankB(const int* __restrict__ RANK,
                                               const int* __restrict__ starts,
                                               const int* __restrict__ ends,
                                               unsigned long long* __restrict__ pk) {
    int i = blockIdx.x * 256 + threadIdx.x;
    pk[RANK[i]] = ((unsigned long long)(unsigned)i << 32) |
                  ((unsigned)starts[i] << 16) | (unsigned)ends[i];
}

// ---------- parallel pairwise-mask precompute ----------
__global__ __launch_bounds__(64) void k_masks(const unsigned long long* __restrict__ pk,
                                              unsigned long long* __restrict__ MC,
                                              unsigned long long* __restrict__ ME,
                                              unsigned long long* __restrict__ MG) {
    int lane = threadIdx.x;
    int c = blockIdx.x;
    unsigned long long p = pk[c * 64 + lane];
    int s = (int)((p >> 16) & 0xFFFF);
    int e = (int)(p & 0xFFFF);
    unsigned long long conf = 0, eqm = 0, gtm = 0;
    for (int r = 1; r < 64; ++r) {
        int j = (lane + r) & 63;
        int sj = __shfl(s, j);
        int ej = __shfl(e, j);
        unsigned long long bit = 1ull << j;
        bool cross = ((sj > s) & (sj <= e) & (ej > e)) |
                     ((ej >= s) & (ej < e) & (sj < s));
        if (cross) conf |= bit;
        if (sj == s) { if (ej == e) eqm |= bit; else if (ej > e) gtm |= bit; }
    }
    MC[c * 64 + lane] = conf;
    ME[c * 64 + lane] = eqm;
    MG[c * 64 + lane] = gtm;
}

// ---------- greedy crossing-suppression scan (masks precomputed) ----------
__global__ __launch_bounds__(64) void k_scan(const unsigned long long* __restrict__ pk,
                                             const unsigned long long* __restrict__ MC,
                                             const unsigned long long* __restrict__ ME,
                                             const unsigned long long* __restrict__ MG,
                                             int top, int* __restrict__ SEL,
                                             int* __restrict__ SELKEY,
                                             int* __restrict__ CNT) {
    __shared__ int mxs[NW];
    __shared__ int mne[NW];
    __shared__ int mxe[NW];
    int lane = threadIdx.x;
    unsigned long long lower = (1ull << lane) - 1ull;
    for (int p = lane; p < NW; p += 64) { mxs[p] = -1; mne[p] = NW; mxe[p] = -1; }
    __syncthreads();
    int count = 0;
    unsigned long long pc = pk[lane];
    unsigned long long conf = MC[lane], eqm = ME[lane], gtm = MG[lane];
    for (int c = 0; c < NS / 64 && count < top; ++c) {
        unsigned long long pn = 0, cn = 0, en2 = 0, gn = 0;
        if (c + 1 < NS / 64) {
            int o = (c + 1) * 64 + lane;
            pn = pk[o]; cn = MC[o]; en2 = ME[o]; gn = MG[o];
        }
        int span = (int)(pc >> 32);
        int s = (int)((pc >> 16) & 0xFFFF);
        int e = (int)(pc & 0xFFFF);
        int bad = (mxs[e] > s) | (mne[s] < e);
        int g = mxe[s];
        bool gdup = (g == e), ggt = (g > e);
        unsigned long long pending = __ballot(!bad), committed = 0;
        unsigned long long relv = (conf | eqm | gtm) & lower;
        while (pending) {
            bool mine = (pending >> lane) & 1;
            bool ready = mine && ((pending & relv) == 0ull);
            unsigned long long cb = committed & lower;
            bool rej = (cb & conf) != 0ull;
            bool gt_any = ggt || ((cb & gtm) != 0ull);
            bool eq_any = gdup || ((cb & eqm) != 0ull);
            bool acc_now = ready && !rej && !(eq_any && !gt_any);
            committed |= __ballot(acc_now);
            pending &= ~__ballot(ready);
        }
        int allowed = top - count;
        while (__popcll(committed) > allowed)
            committed &= ~(1ull << (63 - __builtin_clzll(committed)));
        if ((committed >> lane) & 1) {
            int pos = count + __popcll(committed & lower);
            SEL[pos] = span;
            SELKEY[pos] = s * NW + e;
            atomicMax(&mxe[s], e);
            #pragma unroll
            for (int k = 0; k < MAXW - 1; ++k) {
                if (k < e - s) {
                    atomicMax(&mxs[s + k], s);
                    atomicMin(&mne[s + 1 + k], e);
                }
            }
        }
        count += __popcll(committed);
        __syncthreads();
        pc = pn; conf = cn; eqm = en2; gtm = gn;
    }
    if (lane == 0) *CNT = count;
}

// ---------- final sort: multi-wave rank sort of the selected spans ----------
__global__ __launch_bounds__(512) void k_sort(const int* __restrict__ SEL,
                                              const int* __restrict__ SELKEY,
                                              const int* __restrict__ CNT,
                                              int top, float* __restrict__ out_idx) {
    __shared__ int keys[512];
    __shared__ int vals[512];
    int cnt = *CNT;
    int r = threadIdx.x;
    if (r < top) {
        keys[r] = (r < cnt) ? SELKEY[r] : NW * NW;
        vals[r] = (r < cnt) ? SEL[r] : -1;
    }
    __syncthreads();
    if (r < top) {
        int kr = keys[r];
        int rank = 0;
        for (int q = 0; q < top; ++q) {
            int kq = keys[q];
            rank += (kq < kr) || (kq == kr && q < r);
        }
        out_idx[rank] = (float)vals[r];
    }
}

extern "C" void kernel_launch(void* const* d_in, const int* in_sizes, int n_in,
                              void* d_out, int out_size, void* d_ws, size_t ws_size,
                              hipStream_t stream) {
    const float* doc = (const float*)d_in[0];
    const float* wwe = (const float*)d_in[1];
    const float* wh  = (const float*)d_in[2];
    const float* bh  = (const float*)d_in[3];
    const float* W1  = (const float*)d_in[4];
    const float* b1  = (const float*)d_in[5];
    const float* W2  = (const float*)d_in[6];
    const float* b2  = (const float*)d_in[7];
    const float* W3  = (const float*)d_in[8];
    const float* b3  = (const float*)d_in[9];
    const int* starts = (const int*)d_in[10];
    const int* ends   = (const int*)d_in[11];
    int top = out_size - NS;                 // 409

    float* ws  = (float*)d_ws;
    float* P   = ws + O_P;
    float* P4  = ws + O_P4;
    float* HS  = ws + O_HS;
    float* PS  = ws + O_PS;
    float* H1R = ws + O_H1R;
    ushort* H1H = (ushort*)H1R;
    ushort* H1L = (ushort*)(H1R + 4096000);
    ushort* W1TH = (ushort*)H1R;
    ushort* W1TL = (ushort*)(H1R + 1179648);
    ushort* DOCH = (ushort*)(H1R + 2359296);
    ushort* DOCL = (ushort*)(H1R + 2752512);
    ushort* W2TH = (ushort*)ws;                          // 1024*1024 ushorts (over P)
    ushort* W2TL = (ushort*)(ws + 524288);
    unsigned long long* PK = (unsigned long long*)H1R;   // dead after k_gemm2m
    int* SEL    = (int*)(ws + O_ATT);
    int* SELKEY = SEL + 512;
    int* CNT    = SEL + 1024;
    int* RANK   = SEL + 2048;                            // 8192 ints
    unsigned long long* MC = (unsigned long long*)(ws + O_PS);   // PS dead after k_srank
    unsigned long long* ME = MC + NS;
    unsigned long long* MG = MC + 2 * NS;
    float* outs = (float*)d_out;

    hipMemsetAsync(RANK, 0, NS * sizeof(int), stream);

    k_pre<<<5750, 256, 0, stream>>>(doc, wh, bh, HS, wwe, W1, P4, DOCH, DOCL, W1TH, W1TL);

    k_gemmPm<<<384, 256, 0, stream>>>(DOCH, DOCL, W1TH, W1TL, P);

    k_h1<<<NS, 256, 0, stream>>>(P, P4, HS, b1, starts, ends, H1H, H1L);

    {
        dim3 g(32, 32), b(32, 8);
        k_tw2<<<g, b, 0, stream>>>(W2, W2TH, W2TL);
    }
    k_gemm2m<<<512, 256, 0, stream>>>(H1H, H1L, W2TH, W2TL, b2, W3, PS);

    {
        dim3 g(NS / 256, NS / 256);
        k_srank<<<g, 256, 0, stream>>>(PS, b3, outs, RANK);
    }
    k_rankB<<<NS / 256, 256, 0, stream>>>(RANK, starts, ends, PK);
    k_masks<<<NS / 64, 64, 0, stream>>>(PK, MC, ME, MG);
    k_scan<<<1, 64, 0, stream>>>(PK, MC, ME, MG, top, SEL, SELKEY, CNT);
    k_sort<<<1, 512, 0, stream>>>(SEL, SELKEY, CNT, top, outs + NS);
}

// Round 17
// 211.279 us; speedup vs baseline: 1.1291x; 1.0618x over previous
//
#include <hip/hip_runtime.h>
#include <hip/hip_bf16.h>
#include <stdint.h>

#define NW   1024
#define D    768
#define NS   8192
#define MAXW 30
#define FFNN 1000
#define FEAT 20

typedef __attribute__((ext_vector_type(8))) short bf16x8;
typedef __attribute__((ext_vector_type(4))) float f32x4;
#define MFMA16 __builtin_amdgcn_mfma_f32_16x16x32_bf16

// ws layout (float-slot offsets)
#define O_P    0                          // 3*1024*1000 fp32 P1,P2,P3 (later W2T 1024-stride)
#define O_P4   3072000                    // 30*1000
#define O_HS   3102000                    // 1024
#define O_ATT  3103024                    // RANK region
#define O_PS   3365168                    // 8192*16 (PS; later MC/ME/MG masks)
#define O_H1R  3504432                    // H1 hi/lo bf16; earlier W1T/DOC aliases; later pk

__device__ inline ushort f2b(float v) {
    __hip_bfloat16 b = __float2bfloat16(v);
    return *(ushort*)&b;
}
__device__ inline float b2f(ushort u) {
    __hip_bfloat16 b = *(__hip_bfloat16*)&u;
    return __bfloat162float(b);
}

// ---------- fused pre-pass: head | P4 | doc split | W1 transpose+split | RANK zero ----------
__global__ __launch_bounds__(256) void k_pre(const float* __restrict__ doc,
                                             const float* __restrict__ wh,
                                             const float* __restrict__ bh,
                                             float* __restrict__ hs,
                                             const float* __restrict__ wwe,
                                             const float* __restrict__ W1,
                                             float* __restrict__ P4,
                                             ushort* __restrict__ DOCH,
                                             ushort* __restrict__ DOCL,
                                             ushort* __restrict__ W1TH,
                                             ushort* __restrict__ W1TL,
                                             int* __restrict__ RANK) {
    __shared__ float tile[32][33];
    int b = blockIdx.x;
    int tid = threadIdx.x;
    if (b < 256) {                                    // head: 4 words/block
        int wid = tid >> 6, lane = tid & 63;
        int word = b * 4 + wid;
        const float* row = doc + word * D;
        float acc = 0.f;
        for (int d = lane; d < D; d += 64) acc += row[d] * wh[d];
        #pragma unroll
        for (int o = 32; o; o >>= 1) acc += __shfl_down(acc, o);
        if (lane == 0) hs[word] = acc + bh[0];
    } else if (b < 374) {                             // P4
        int o = (b - 256) * 256 + tid;
        if (o >= 30 * FFNN) return;
        int wi = o / FFNN, j = o - wi * FFNN;
        float acc = 0.f;
        #pragma unroll
        for (int f = 0; f < FEAT; ++f) acc += wwe[wi * FEAT + f] * W1[(1536 + f) * FFNN + j];
        P4[o] = acc;
    } else if (b < 3446) {                            // doc split
        int i = (b - 374) * 256 + tid;
        if (i >= NW * D) return;
        float v = doc[i];
        ushort hi = f2b(v);
        float r = v - b2f(hi);
        DOCH[i] = hi;
        DOCL[i] = f2b(r);
    } else if (b < 5750) {                            // W1 transpose+split (2304 blocks)
        int lb = b - 3446;
        int z = lb / 768, rem = lb - z * 768;
        int ny = rem / 24, kx = rem - ny * 24;
        int k0 = kx * 32, n0 = ny * 32;
        int tx = tid & 31, ty = tid >> 5;
        int roff = (z == 0) ? 0 : (z == 1) ? 768 : 1556;
        #pragma unroll
        for (int i = 0; i < 4; ++i) {
            int kk = ty + i * 8;
            float v = (n0 + tx < FFNN) ? W1[(size_t)(roff + k0 + kk) * FFNN + n0 + tx] : 0.f;
            tile[kk][tx] = v;
        }
        __syncthreads();
        #pragma unroll
        for (int i = 0; i < 4; ++i) {
            int nn = ty + i * 8;
            float v = tile[tx][nn];
            ushort hi = f2b(v);
            float r = v - b2f(hi);
            size_t o = (size_t)z * 1024 * D + (size_t)(n0 + nn) * D + k0 + tx;
            W1TH[o] = hi;
            W1TL[o] = f2b(r);
        }
    } else {                                          // RANK zero (32 blocks: 8192 ints)
        RANK[(b - 5750) * 256 + tid] = 0;
    }
}

// ---------- W2: transpose + split -> W2T[1024 n][1024 k] hi/lo, zero-padded k ----------
__global__ void k_tw2(const float* __restrict__ W2,
                      ushort* __restrict__ TH, ushort* __restrict__ TL) {
    __shared__ float tile[32][33];
    int tx = threadIdx.x, ty = threadIdx.y;
    int k0 = blockIdx.x * 32, n0 = blockIdx.y * 32;
    #pragma unroll
    for (int i = 0; i < 4; ++i) {
        int kk = ty + i * 8;
        float v = (k0 + kk < FFNN && n0 + tx < FFNN)
                    ? W2[(size_t)(k0 + kk) * FFNN + n0 + tx] : 0.f;
        tile[kk][tx] = v;
    }
    __syncthreads();
    #pragma unroll
    for (int i = 0; i < 4; ++i) {
        int nn = ty + i * 8;
        int k = k0 + tx;
        float v = tile[tx][nn];
        ushort hi = f2b(v);
        float r = v - b2f(hi);
        size_t o = (size_t)(n0 + nn) * 1024 + k;
        TH[o] = hi;
        TL[o] = f2b(r);
    }
}

// ---------- MFMA GEMM: P[z] = doc @ W1slice  (128x64 tile, 384 blocks, dbuf+lds-direct) ----------
__global__ __launch_bounds__(256) void k_gemmPm(const ushort* __restrict__ Ah_g,
                                                const ushort* __restrict__ Al_g,
                                                const ushort* __restrict__ Bh_g,
                                                const ushort* __restrict__ Bl_g,
                                                float* __restrict__ Pout) {
    __shared__ ushort LDS[2][12288];
    int tid = threadIdx.x;
    int orig = blockIdx.x;                    // 384 = 8 XCD * 48
    int t = (orig & 7) * 48 + (orig >> 3);
    int pair = t >> 4, colt = t & 15;
    int z = pair >> 3, rowt = pair & 7;
    int row0 = rowt * 128, col0 = colt * 64;
    size_t zoff = (size_t)z * 1024 * D;
    const ushort* Bh_z = Bh_g + zoff;
    const ushort* Bl_z = Bl_g + zoff;
    float* C = Pout + (size_t)z * NW * FFNN;
    int w = tid >> 6, l = tid & 63;
    int wr = w >> 1, wc = w & 1;
    int fr = l & 15, kb = l >> 4;
    int rA = tid >> 2, p = tid & 3;
    int q = p ^ ((rA >> 1) & 3);
    f32x4 acc[4][2] = {};
    int cur = 0;
    #define STAGE_P(d, kt)                                                                  \
        do {                                                                                \
            int kg = (kt) + q * 8;                                                          \
            __builtin_amdgcn_global_load_lds((const uint*)(Ah_g + (size_t)(row0 + rA) * D + kg),      (uint*)&LDS[d][(0 * 256 + tid) * 8], 16, 0, 0); \
            __builtin_amdgcn_global_load_lds((const uint*)(Ah_g + (size_t)(row0 + rA + 64) * D + kg), (uint*)&LDS[d][(1 * 256 + tid) * 8], 16, 0, 0); \
            __builtin_amdgcn_global_load_lds((const uint*)(Al_g + (size_t)(row0 + rA) * D + kg),      (uint*)&LDS[d][(2 * 256 + tid) * 8], 16, 0, 0); \
            __builtin_amdgcn_global_load_lds((const uint*)(Al_g + (size_t)(row0 + rA + 64) * D + kg), (uint*)&LDS[d][(3 * 256 + tid) * 8], 16, 0, 0); \
            __builtin_amdgcn_global_load_lds((const uint*)(Bh_z + (size_t)(col0 + rA) * D + kg),      (uint*)&LDS[d][(4 * 256 + tid) * 8], 16, 0, 0); \
            __builtin_amdgcn_global_load_lds((const uint*)(Bl_z + (size_t)(col0 + rA) * D + kg),      (uint*)&LDS[d][(5 * 256 + tid) * 8], 16, 0, 0); \
        } while (0)
    STAGE_P(0, 0);
    __syncthreads();
    for (int kt = 0; kt < D; kt += 32) {
        if (kt + 32 < D) STAGE_P(cur ^ 1, kt + 32);
        bf16x8 af[4], alf[4], bfr[2], blf[2];
        #pragma unroll
        for (int mt = 0; mt < 4; ++mt) {
            int r = wr * 64 + mt * 16 + fr;
            int sl = (kb ^ ((r >> 1) & 3)) * 8;
            af[mt]  = *(const bf16x8*)&LDS[cur][r * 32 + sl];
            alf[mt] = *(const bf16x8*)&LDS[cur][4096 + r * 32 + sl];
        }
        #pragma unroll
        for (int nt = 0; nt < 2; ++nt) {
            int c = wc * 32 + nt * 16 + fr;
            int sl = (kb ^ ((c >> 1) & 3)) * 8;
            bfr[nt] = *(const bf16x8*)&LDS[cur][8192 + c * 32 + sl];
            blf[nt] = *(const bf16x8*)&LDS[cur][10240 + c * 32 + sl];
        }
        #pragma unroll
        for (int mt = 0; mt < 4; ++mt)
            #pragma unroll
            for (int nt = 0; nt < 2; ++nt) {
                acc[mt][nt] = MFMA16(af[mt], bfr[nt], acc[mt][nt], 0, 0, 0);
                acc[mt][nt] = MFMA16(af[mt], blf[nt], acc[mt][nt], 0, 0, 0);
                acc[mt][nt] = MFMA16(alf[mt], bfr[nt], acc[mt][nt], 0, 0, 0);
            }
        __syncthreads();
        cur ^= 1;
    }
    #pragma unroll
    for (int mt = 0; mt < 4; ++mt)
        #pragma unroll
        for (int nt = 0; nt < 2; ++nt)
            #pragma unroll
            for (int r = 0; r < 4; ++r) {
                int row = row0 + wr * 64 + mt * 16 + kb * 4 + r;
                int col = col0 + wc * 32 + nt * 16 + fr;
                if (col < FFNN) C[(size_t)row * FFNN + col] = acc[mt][nt][r];
            }
}

// ---------- MFMA GEMM2 fused: relu(H1@W2+b2).W3 -> PS (dbuf + global_load_lds) ----------
__global__ __launch_bounds__(256) void k_gemm2m(const ushort* __restrict__ Ah_g,
                                                const ushort* __restrict__ Al_g,
                                                const ushort* __restrict__ Bh_g,
                                                const ushort* __restrict__ Bl_g,
                                                const float* __restrict__ b2,
                                                const float* __restrict__ W3,
                                                float* __restrict__ PS) {
    __shared__ ushort LDS[2][4][128 * 32];
    int tid = threadIdx.x;
    int orig = blockIdx.x;                    // 512 = 8 XCD * 64; XCD owns 8-row band
    int xcd = orig & 7, idx = orig >> 3;
    int rowt = xcd * 8 + (idx & 7), colt = idx >> 3;
    int row0 = rowt * 128, col0 = colt * 128;
    int w = tid >> 6, l = tid & 63;
    int wr = w >> 1, wc = w & 1;
    int fr = l & 15, kb = l >> 4;
    int r0 = tid >> 2, p = tid & 3;
    int r1 = r0 + 64;
    int q0 = p ^ ((r0 >> 1) & 3);
    int q1 = p ^ ((r1 >> 1) & 3);
    int base0 = (w * 64) * 8;
    int base1 = (256 + w * 64) * 8;
    f32x4 acc[4][4] = {};
    int cur = 0;
    #define STAGE_2(d, kt)                                                                  \
        do {                                                                                \
            int kg0 = (kt) + q0 * 8, kg1 = (kt) + q1 * 8;                                   \
            __builtin_amdgcn_global_load_lds((const uint*)(Ah_g + (size_t)(row0 + r0) * 1000 + kg0), (uint*)&LDS[d][0][base0], 16, 0, 0); \
            __builtin_amdgcn_global_load_lds((const uint*)(Al_g + (size_t)(row0 + r0) * 1000 + kg0), (uint*)&LDS[d][1][base0], 16, 0, 0); \
            __builtin_amdgcn_global_load_lds((const uint*)(Bh_g + (size_t)(col0 + r0) * 1024 + kg0), (uint*)&LDS[d][2][base0], 16, 0, 0); \
            __builtin_amdgcn_global_load_lds((const uint*)(Bl_g + (size_t)(col0 + r0) * 1024 + kg0), (uint*)&LDS[d][3][base0], 16, 0, 0); \
            __builtin_amdgcn_global_load_lds((const uint*)(Ah_g + (size_t)(row0 + r1) * 1000 + kg1), (uint*)&LDS[d][0][base1], 16, 0, 0); \
            __builtin_amdgcn_global_load_lds((const uint*)(Al_g + (size_t)(row0 + r1) * 1000 + kg1), (uint*)&LDS[d][1][base1], 16, 0, 0); \
            __builtin_amdgcn_global_load_lds((const uint*)(Bh_g + (size_t)(col0 + r1) * 1024 + kg1), (uint*)&LDS[d][2][base1], 16, 0, 0); \
            __builtin_amdgcn_global_load_lds((const uint*)(Bl_g + (size_t)(col0 + r1) * 1024 + kg1), (uint*)&LDS[d][3][base1], 16, 0, 0); \
        } while (0)
    STAGE_2(0, 0);
    __syncthreads();
    for (int kt = 0; kt < 1024; kt += 32) {
        if (kt + 32 < 1024) STAGE_2(cur ^ 1, kt + 32);
        bf16x8 af[4], alf[4], bfr[4], blf[4];
        #pragma unroll
        for (int mt = 0; mt < 4; ++mt) {
            int r = wr * 64 + mt * 16 + fr;
            int sl = (kb ^ ((r >> 1) & 3)) * 8;
            af[mt]  = *(const bf16x8*)&LDS[cur][0][r * 32 + sl];
            alf[mt] = *(const bf16x8*)&LDS[cur][1][r * 32 + sl];
        }
        #pragma unroll
        for (int nt = 0; nt < 4; ++nt) {
            int c = wc * 64 + nt * 16 + fr;
            int sl = (kb ^ ((c >> 1) & 3)) * 8;
            bfr[nt] = *(const bf16x8*)&LDS[cur][2][c * 32 + sl];
            blf[nt] = *(const bf16x8*)&LDS[cur][3][c * 32 + sl];
        }
        #pragma unroll
        for (int mt = 0; mt < 4; ++mt)
            #pragma unroll
            for (int nt = 0; nt < 4; ++nt) {
                acc[mt][nt] = MFMA16(af[mt], bfr[nt], acc[mt][nt], 0, 0, 0);
                acc[mt][nt] = MFMA16(af[mt], blf[nt], acc[mt][nt], 0, 0, 0);
                acc[mt][nt] = MFMA16(alf[mt], bfr[nt], acc[mt][nt], 0, 0, 0);
            }
        __syncthreads();
        cur ^= 1;
    }
    float w3v[4], b2v[4];
    #pragma unroll
    for (int nt = 0; nt < 4; ++nt) {
        int col = col0 + wc * 64 + nt * 16 + fr;
        bool cv = col < FFNN;
        w3v[nt] = cv ? W3[col] : 0.f;
        b2v[nt] = cv ? b2[col] : 0.f;
    }
    #pragma unroll
    for (int mt = 0; mt < 4; ++mt) {
        #pragma unroll
        for (int r = 0; r < 4; ++r) {
            float pp = 0.f;
            #pragma unroll
            for (int nt = 0; nt < 4; ++nt) {
                float v = fmaxf(acc[mt][nt][r] + b2v[nt], 0.f);
                pp = fmaf(v, w3v[nt], pp);
            }
            pp += __shfl_xor(pp, 1);
            pp += __shfl_xor(pp, 2);
            pp += __shfl_xor(pp, 4);
            pp += __shfl_xor(pp, 8);
            if (fr == 0) {
                int row = row0 + wr * 64 + mt * 16 + kb * 4 + r;
                PS[row * 16 + colt * 2 + wc] = pp;
            }
        }
    }
}

// ---------- h1 assembly (attn fused): softmax + gather P rows + bias + relu -> bf16 hi/lo ----------
__global__ __launch_bounds__(256) void k_h1(const float* __restrict__ P,
                                            const float* __restrict__ P4,
                                            const float* __restrict__ hs,
                                            const float* __restrict__ b1,
                                            const int* __restrict__ starts,
                                            const int* __restrict__ ends,
                                            ushort* __restrict__ H1h,
                                            ushort* __restrict__ H1l) {
    __shared__ float shs[32];
    int s = blockIdx.x;
    int tid = threadIdx.x;
    int st = starts[s], en = ends[s];
    int width = en - st + 1;
    if (tid < MAXW) {
        int idx = st + tid; if (idx > NW - 1) idx = NW - 1;
        shs[tid] = hs[idx];
    }
    __syncthreads();
    float v[MAXW];
    float mx = -3.0e38f;
    #pragma unroll
    for (int w = 0; w < MAXW; ++w) {
        float x = shs[w];
        v[w] = (w < width) ? x : -3.0e38f;
        mx = fmaxf(mx, v[w]);
    }
    float sum = 0.f;
    #pragma unroll
    for (int w = 0; w < MAXW; ++w) { v[w] = expf(v[w] - mx); sum += v[w]; }
    float inv = 1.f / sum;
    if (tid >= 250) return;
    const float4* P1r = (const float4*)(P + (size_t)st * FFNN);
    const float4* P2r = (const float4*)(P + (size_t)NW * FFNN + (size_t)en * FFNN);
    const float*  P3  = P + 2 * (size_t)NW * FFNN;
    const float4* P4r = (const float4*)(P4 + (size_t)(width - 1) * FFNN);
    const float4* b1v = (const float4*)b1;
    float4 a = P1r[tid], b = P2r[tid], c = P4r[tid], d = b1v[tid];
    float4 acc = {a.x + b.x + c.x + d.x,
                  a.y + b.y + c.y + d.y,
                  a.z + b.z + c.z + d.z,
                  a.w + b.w + c.w + d.w};
    for (int w = 0; w < width; ++w) {
        float aw = v[w] * inv;
        float4 p3 = ((const float4*)(P3 + (size_t)(st + w) * FFNN))[tid];
        acc.x = fmaf(aw, p3.x, acc.x);
        acc.y = fmaf(aw, p3.y, acc.y);
        acc.z = fmaf(aw, p3.z, acc.z);
        acc.w = fmaf(aw, p3.w, acc.w);
    }
    float rv[4] = {fmaxf(acc.x, 0.f), fmaxf(acc.y, 0.f), fmaxf(acc.z, 0.f), fmaxf(acc.w, 0.f)};
    ushort4 hi, lo;
    ushort* hp = (ushort*)&hi;
    ushort* lp = (ushort*)&lo;
    #pragma unroll
    for (int j = 0; j < 4; ++j) {
        ushort h = f2b(rv[j]);
        float r = rv[j] - b2f(h);
        hp[j] = h;
        lp[j] = f2b(r);
    }
    *(ushort4*)(H1h + (size_t)s * FFNN + tid * 4) = hi;
    *(ushort4*)(H1l + (size_t)s * FFNN + tid * 4) = lo;
}

// ---------- fused score + tile-parallel rank ----------
__global__ __launch_bounds__(256) void k_srank(const float* __restrict__ PS,
                                               const float* __restrict__ b3,
                                               float* __restrict__ out,
                                               int* __restrict__ RANK) {
    __shared__ unsigned long long tile[256];
    int i = blockIdx.x * 256 + threadIdx.x;
    int j = blockIdx.y * 256 + threadIdx.x;
    float b3v = b3[0];
    float sj = 0.f;
    #pragma unroll
    for (int b = 0; b < 16; ++b) sj += PS[j * 16 + b];
    sj += b3v;
    unsigned uj = __float_as_uint(sj);
    unsigned mj = (uj >> 31) ? ~uj : (uj | 0x80000000u);
    tile[threadIdx.x] = ((unsigned long long)(~mj) << 32) | (unsigned)j;
    float si = 0.f;
    #pragma unroll
    for (int b = 0; b < 16; ++b) si += PS[i * 16 + b];
    si += b3v;
    if (blockIdx.y == 0) out[i] = si;
    __syncthreads();
    unsigned u = __float_as_uint(si);
    unsigned m = (u >> 31) ? ~u : (u | 0x80000000u);
    unsigned long long key = ((unsigned long long)(~m) << 32) | (unsigned)i;
    int r = 0;
    #pragma unroll 8
    for (int q = 0; q < 256; ++q) r += (tile[q] < key);
    if (r) atomicAdd(&RANK[i], r);
}

// ---------- scatter: pk[RANK[i]] = packed (span, start, end) ----------
__global__ __launch_bounds__(256) void k_rankB(const int* __restrict__ RANK,
                                               const int* __restrict__ starts,
                                               const int* __restrict__ ends,
                                               unsigned long long* __restrict__ pk) {
    int i = blockIdx.x * 256 + threadIdx.x;
    pk[RANK[i]] = ((unsigned long long)(unsigned)i << 32) |
                  ((unsigned)starts[i] << 16) | (unsigned)ends[i];
}

// ---------- parallel pairwise-mask precompute ----------
__global__ __launch_bounds__(64) void k_masks(const unsigned long long* __restrict__ pk,
                                              unsigned long long* __restrict__ MC,
                                              unsigned long long* __restrict__ ME,
                                              unsigned long long* __restrict__ MG) {
    int lane = threadIdx.x;
    int c = blockIdx.x;
    unsigned long long p = pk[c * 64 + lane];
    int s = (int)((p >> 16) & 0xFFFF);
    int e = (int)(p & 0xFFFF);
    unsigned long long conf = 0, eqm = 0, gtm = 0;
    for (int r = 1; r < 64; ++r) {
        int j = (lane + r) & 63;
        int sj = __shfl(s, j);
        int ej = __shfl(e, j);
        unsigned long long bit = 1ull << j;
        bool cross = ((sj > s) & (sj <= e) & (ej > e)) |
                     ((ej >= s) & (ej < e) & (sj < s));
        if (cross) conf |= bit;
        if (sj == s) { if (ej == e) eqm |= bit; else if (ej > e) gtm |= bit; }
    }
    MC[c * 64 + lane] = conf;
    ME[c * 64 + lane] = eqm;
    MG[c * 64 + lane] = gtm;
}

// ---------- greedy scan (wave 0, barrier-free) + fused 8-wave final sort ----------
__global__ __launch_bounds__(512) void k_scan(const unsigned long long* __restrict__ pk,
                                              const unsigned long long* __restrict__ MC,
                                              const unsigned long long* __restrict__ ME,
                                              const unsigned long long* __restrict__ MG,
                                              int top, float* __restrict__ out_idx) {
    __shared__ int mxs[NW];
    __shared__ int mne[NW];
    __shared__ int mxe[NW];
    __shared__ int sel[512];
    __shared__ int selkey[512];
    int tid = threadIdx.x;
    for (int p = tid; p < NW; p += 512) { mxs[p] = -1; mne[p] = NW; mxe[p] = -1; }
    if (tid < 512) { sel[tid] = -1; selkey[tid] = NW * NW; }
    __syncthreads();
    if (tid < 64) {                                   // wave 0: serial scan, barrier-free
        int lane = tid;
        unsigned long long lower = (1ull << lane) - 1ull;
        int count = 0;
        unsigned long long pc = pk[lane];
        unsigned long long conf = MC[lane], eqm = ME[lane], gtm = MG[lane];
        for (int c = 0; c < NS / 64 && count < top; ++c) {
            unsigned long long pn = 0, cn = 0, en2 = 0, gn = 0;
            if (c + 1 < NS / 64) {
                int o = (c + 1) * 64 + lane;
                pn = pk[o]; cn = MC[o]; en2 = ME[o]; gn = MG[o];
            }
            int span = (int)(pc >> 32);
            int s = (int)((pc >> 16) & 0xFFFF);
            int e = (int)(pc & 0xFFFF);
            int bad = (mxs[e] > s) | (mne[s] < e);
            int g = mxe[s];
            bool gdup = (g == e), ggt = (g > e);
            unsigned long long pending = __ballot(!bad), committed = 0;
            unsigned long long relv = (conf | eqm | gtm) & lower;
            while (pending) {
                bool mine = (pending >> lane) & 1;
                bool ready = mine && ((pending & relv) == 0ull);
                unsigned long long cb = committed & lower;
                bool rej = (cb & conf) != 0ull;
                bool gt_any = ggt || ((cb & gtm) != 0ull);
                bool eq_any = gdup || ((cb & eqm) != 0ull);
                bool acc_now = ready && !rej && !(eq_any && !gt_any);
                committed |= __ballot(acc_now);
                pending &= ~__ballot(ready);
            }
            int allowed = top - count;
            while (__popcll(committed) > allowed)
                committed &= ~(1ull << (63 - __builtin_clzll(committed)));
            if ((committed >> lane) & 1) {
                int pos = count + __popcll(committed & lower);
                sel[pos] = span;
                selkey[pos] = s * NW + e;
                atomicMax(&mxe[s], e);
                #pragma unroll
                for (int k = 0; k < MAXW - 1; ++k) {
                    if (k < e - s) {
                        atomicMax(&mxs[s + k], s);
                        atomicMin(&mne[s + 1 + k], e);
                    }
                }
            }
            count += __popcll(committed);
            pc = pn; conf = cn; eqm = en2; gtm = gn;
        }
    }
    __syncthreads();
    // 8-wave stable rank-sort of sel[0..top)
    int r = tid;
    if (r < top) {
        int kr = selkey[r];
        int rank = 0;
        for (int q = 0; q < top; ++q) {
            int kq = selkey[q];
            rank += (kq < kr) || (kq == kr && q < r);
        }
        out_idx[rank] = (float)sel[r];
    }
}

extern "C" void kernel_launch(void* const* d_in, const int* in_sizes, int n_in,
                              void* d_out, int out_size, void* d_ws, size_t ws_size,
                              hipStream_t stream) {
    const float* doc = (const float*)d_in[0];
    const float* wwe = (const float*)d_in[1];
    const float* wh  = (const float*)d_in[2];
    const float* bh  = (const float*)d_in[3];
    const float* W1  = (const float*)d_in[4];
    const float* b1  = (const float*)d_in[5];
    const float* W2  = (const float*)d_in[6];
    const float* b2  = (const float*)d_in[7];
    const float* W3  = (const float*)d_in[8];
    const float* b3  = (const float*)d_in[9];
    const int* starts = (const int*)d_in[10];
    const int* ends   = (const int*)d_in[11];
    int top = out_size - NS;                 // 409

    float* ws  = (float*)d_ws;
    float* P   = ws + O_P;
    float* P4  = ws + O_P4;
    float* HS  = ws + O_HS;
    float* PS  = ws + O_PS;
    float* H1R = ws + O_H1R;
    ushort* H1H = (ushort*)H1R;
    ushort* H1L = (ushort*)(H1R + 4096000);
    ushort* W1TH = (ushort*)H1R;
    ushort* W1TL = (ushort*)(H1R + 1179648);
    ushort* DOCH = (ushort*)(H1R + 2359296);
    ushort* DOCL = (ushort*)(H1R + 2752512);
    ushort* W2TH = (ushort*)ws;                          // 1024*1024 ushorts (over P)
    ushort* W2TL = (ushort*)(ws + 524288);
    unsigned long long* PK = (unsigned long long*)H1R;   // dead after k_gemm2m
    int* RANK   = (int*)(ws + O_ATT);                    // 8192 ints
    unsigned long long* MC = (unsigned long long*)(ws + O_PS);   // PS dead after k_srank
    unsigned long long* ME = MC + NS;
    unsigned long long* MG = MC + 2 * NS;
    float* outs = (float*)d_out;

    k_pre<<<5782, 256, 0, stream>>>(doc, wh, bh, HS, wwe, W1, P4, DOCH, DOCL, W1TH, W1TL, RANK);

    k_gemmPm<<<384, 256, 0, stream>>>(DOCH, DOCL, W1TH, W1TL, P);

    k_h1<<<NS, 256, 0, stream>>>(P, P4, HS, b1, starts, ends, H1H, H1L);

    {
        dim3 g(32, 32), b(32, 8);
        k_tw2<<<g, b, 0, stream>>>(W2, W2TH, W2TL);
    }
    k_gemm2m<<<512, 256, 0, stream>>>(H1H, H1L, W2TH, W2TL, b2, W3, PS);

    {
        dim3 g(NS / 256, NS / 256);
        k_srank<<<g, 256, 0, stream>>>(PS, b3, outs, RANK);
    }
    k_rankB<<<NS / 256, 256, 0, stream>>>(RANK, starts, ends, PK);
    k_masks<<<NS / 64, 64, 0, stream>>>(PK, MC, ME, MG);
    k_scan<<<1, 512, 0, stream>>>(PK, MC, ME, MG, top, outs + NS);
}